// Round 8
// baseline (268.523 us; speedup 1.0000x reference)
//
#include <hip/hip_runtime.h>
#include <cstdint>

typedef unsigned short u16;
typedef __attribute__((ext_vector_type(8))) short bf16x8;
typedef __attribute__((ext_vector_type(8))) unsigned short u16x8;
typedef __attribute__((ext_vector_type(4))) float f32x4;

constexpr int B_  = 8;
constexpr int C_  = 128;
constexpr int T_  = 8;
constexpr int HW_ = 1024;
constexpr int P_  = T_ * HW_;   // 8192 positions per (b,c)
constexpr int F_  = 128;        // PAM feature dim (K-order: f'' = t*16 + cq)
constexpr int CT_ = C_ * T_;    // 1024

static __device__ __forceinline__ u16 f2bf(float f) {
    union { float f; unsigned u; } v; v.f = f;
    unsigned r = v.u + 0x7fffu + ((v.u >> 16) & 1u);   // RNE
    return (u16)(r >> 16);
}
static __device__ __forceinline__ float bf2f(u16 h) {
    union { unsigned u; float f; } v; v.u = ((unsigned)h) << 16;
    return v.f;
}

#define GLOAD16(src, dst)                                                     \
    __builtin_amdgcn_global_load_lds(                                         \
        (const __attribute__((address_space(1))) void*)(src),                 \
        (__attribute__((address_space(3))) void*)(dst), 16, 0, 0)

// ---------------------------------------------------------------------------
// TIM gram, restructured: grid (64,8), block = (b, 2 channels), float4 loads,
// 36 upper-triangle accumulators, atomic combine. Block (0,0) casts Wall.
// ---------------------------------------------------------------------------
__global__ __launch_bounds__(256)
void k_tim_gram(const float* __restrict__ x, float* __restrict__ e_t,
                const float* __restrict__ Wq, const float* __restrict__ Wk,
                const float* __restrict__ Wv, u16* __restrict__ Wall)
{
    const int b = blockIdx.y, cc = blockIdx.x;     // cc: 2 channels
    const int tid = threadIdx.x;

    if (cc == 0 && b == 0) {
        for (int i = tid; i < 20480; i += 256) {
            int oc = i >> 7, c2 = i & 127;
            float wv;
            if (oc < 16)      wv = Wq[oc * 128 + c2];
            else if (oc < 32) wv = Wk[(oc - 16) * 128 + c2];
            else              wv = Wv[(oc - 32) * 128 + c2];
            Wall[i] = f2bf(wv);
        }
    }

    const int hw = tid * 4;
    float4 xv[2][8];
    #pragma unroll
    for (int ci = 0; ci < 2; ci++) {
        const float* xb = x + ((size_t)(b * C_ + cc * 2 + ci)) * P_;
        #pragma unroll
        for (int t = 0; t < 8; t++)
            xv[ci][t] = *(const float4*)&xb[t * HW_ + hw];
    }

    float acc[36];
    #pragma unroll
    for (int p = 0; p < 36; p++) acc[p] = 0.f;
    #pragma unroll
    for (int ci = 0; ci < 2; ci++) {
        int p = 0;
        #pragma unroll
        for (int t = 0; t < 8; t++)
            #pragma unroll
            for (int s = t; s < 8; s++) {
                float4 a = xv[ci][t], c4 = xv[ci][s];
                acc[p++] += a.x * c4.x + a.y * c4.y + a.z * c4.z + a.w * c4.w;
            }
    }

    const int lane = tid & 63, w = tid >> 6;
    #pragma unroll
    for (int p = 0; p < 36; p++)
        #pragma unroll
        for (int off = 32; off; off >>= 1)
            acc[p] += __shfl_xor(acc[p], off);

    __shared__ float sm[4][36];
    if (lane == 0)
        #pragma unroll
        for (int p = 0; p < 36; p++) sm[w][p] = acc[p];
    __syncthreads();
    if (tid < 36) {
        float v = sm[0][tid] + sm[1][tid] + sm[2][tid] + sm[3][tid];
        int t = 0, rem = tid;
        while (rem >= 8 - t) { rem -= 8 - t; t++; }
        int s = t + rem;
        atomicAdd(&e_t[b * 64 + t * 8 + s], v);
        if (s != t) atomicAdd(&e_t[b * 64 + s * 8 + t], v);
    }
}

// ---------------------------------------------------------------------------
// Fused prep: xhi/xlo [c][p], xT [p][c]; QKV via MFMA from LDS x-tile.
// q/k written K-contig (f''=t*16+cq) via LDS transpose, coalesced 16B stores.
// ---------------------------------------------------------------------------
__global__ __launch_bounds__(256)
void k_prep(const float* __restrict__ x, u16* __restrict__ xT,
            u16* __restrict__ xhi, u16* __restrict__ xlo,
            const u16* __restrict__ Wall,
            const float* __restrict__ bq, const float* __restrict__ bk,
            const float* __restrict__ bv,
            u16* __restrict__ qt, u16* __restrict__ kt, u16* __restrict__ v16)
{
    __shared__ char sy[32768];                 // [128 p][128 c] bf16, swizzled
    const int b  = blockIdx.y;
    const int p0 = blockIdx.x * 128;
    const int tid = threadIdx.x, lane = tid & 63, w = tid >> 6;

    #pragma unroll
    for (int r = 0; r < 16; r++) {
        int lin = r * 256 + tid;
        int c = lin >> 5, j4 = (lin & 31) << 2;
        size_t gi = ((size_t)(b * C_ + c)) * P_ + p0 + j4;
        float4 xv = *(const float4*)&x[gi];
        float a4[4] = {xv.x, xv.y, xv.z, xv.w};
        ushort4 h, l;
        h.x = f2bf(a4[0]); h.y = f2bf(a4[1]);
        h.z = f2bf(a4[2]); h.w = f2bf(a4[3]);
        l.x = f2bf(a4[0] - bf2f(h.x)); l.y = f2bf(a4[1] - bf2f(h.y));
        l.z = f2bf(a4[2] - bf2f(h.z)); l.w = f2bf(a4[3] - bf2f(h.w));
        *(ushort4*)&xhi[gi] = h;
        *(ushort4*)&xlo[gi] = l;
        #pragma unroll
        for (int u = 0; u < 4; u++) {
            int pi = j4 + u;
            int byte = pi * 256 + ((c * 2) ^ (((pi >> 2) & 15) << 4));
            *(u16*)(sy + byte) = (u == 0) ? h.x : (u == 1) ? h.y
                               : (u == 2) ? h.z : h.w;
        }
    }
    __syncthreads();

    // xT (K-contiguous in c) for cam_av
    #pragma unroll
    for (int r = 0; r < 8; r++) {
        int lin = r * 256 + tid;
        int pi = lin >> 4, ci8 = (lin & 15) << 3;
        bf16x8 v = *(const bf16x8*)(sy + pi * 256 +
                                    ((ci8 * 2) ^ (((pi >> 2) & 15) << 4)));
        *(bf16x8*)&xT[((size_t)(b * P_ + p0 + pi)) * C_ + ci8] = v;
    }

    // ---- QKV MFMA: A = Wall rows (global, L2-hot), B = sy tile ----
    bf16x8 bg[4][2];
    #pragma unroll
    for (int ks = 0; ks < 4; ks++)
        #pragma unroll
        for (int ni = 0; ni < 2; ni++) {
            int p  = w * 32 + ni * 16 + (lane & 15);
            int cb = (ks * 32 + (lane >> 4) * 8) * 2;     // byte col
            bg[ks][ni] = *(const bf16x8*)(sy + p * 256 +
                              (cb ^ (((p >> 2) & 15) << 4)));
        }
    __syncthreads();   // all sy reads complete; sy reusable after this point

    f32x4 acc[10][2];
    #pragma unroll
    for (int mi = 0; mi < 10; mi++) {
        acc[mi][0] = (f32x4){0.f, 0.f, 0.f, 0.f};
        acc[mi][1] = (f32x4){0.f, 0.f, 0.f, 0.f};
    }

    #pragma unroll
    for (int mi = 0; mi < 10; mi++) {
        #pragma unroll
        for (int ks = 0; ks < 4; ks++) {
            bf16x8 af = *(const bf16x8*)(Wall + (mi * 16 + (lane & 15)) * 128
                                          + ks * 32 + (lane >> 4) * 8);
            acc[mi][0] = __builtin_amdgcn_mfma_f32_16x16x32_bf16(
                af, bg[ks][0], acc[mi][0], 0, 0, 0);
            acc[mi][1] = __builtin_amdgcn_mfma_f32_16x16x32_bf16(
                af, bg[ks][1], acc[mi][1], 0, 0, 0);
        }
    }

    const int t      = p0 >> 10;
    const int hw0    = p0 & 1023;
    const int hwbase = hw0 + w * 32;

    // v (mi 2..9): 32B-chunk writes as before
    #pragma unroll
    for (int mi = 2; mi < 10; mi++)
        #pragma unroll
        for (int ni = 0; ni < 2; ni++)
            #pragma unroll
            for (int r = 0; r < 4; r++) {
                int oc = mi * 16 + (lane >> 4) * 4 + r;
                int hw = hwbase + ni * 16 + (lane & 15);
                v16[((size_t)(b * C_ + oc - 32)) * P_ + t * HW_ + hw] =
                    f2bf(acc[mi][ni][r] + bv[oc - 32]);
            }

    // q/k (mi 0,1): LDS transpose -> coalesced 16B stores, f'' = t*16+cq
    u16* qk = (u16*)sy;                        // [2][128 hw][24] (48B rows)
    #pragma unroll
    for (int mi = 0; mi < 2; mi++)
        #pragma unroll
        for (int ni = 0; ni < 2; ni++) {
            int hwl = w * 32 + ni * 16 + (lane & 15);
            int cq0 = (lane >> 4) * 4;
            ushort4 pk;
            float b0 = (mi == 0) ? bq[cq0 + 0] : bk[cq0 + 0];
            float b1 = (mi == 0) ? bq[cq0 + 1] : bk[cq0 + 1];
            float b2 = (mi == 0) ? bq[cq0 + 2] : bk[cq0 + 2];
            float b3 = (mi == 0) ? bq[cq0 + 3] : bk[cq0 + 3];
            pk.x = f2bf(acc[mi][ni][0] + b0);
            pk.y = f2bf(acc[mi][ni][1] + b1);
            pk.z = f2bf(acc[mi][ni][2] + b2);
            pk.w = f2bf(acc[mi][ni][3] + b3);
            *(ushort4*)&qk[(mi * 128 + hwl) * 24 + cq0] = pk;
        }
    __syncthreads();
    {
        int mi = tid >> 7, hwl = tid & 127;
        u16x8 lo = *(const u16x8*)&qk[(mi * 128 + hwl) * 24 + 0];
        u16x8 hi = *(const u16x8*)&qk[(mi * 128 + hwl) * 24 + 8];
        u16* dst = (mi == 0) ? qt : kt;
        size_t off = ((size_t)b * HW_ + hw0 + hwl) * F_ + t * 16;
        *(u16x8*)&dst[off]     = lo;
        *(u16x8*)&dst[off + 8] = hi;
    }
}

// ---------------------------------------------------------------------------
// Fused energy+softmax: block = 16 n-rows x 1024 m, E stays in registers.
// Output staged in LDS, dumped with coalesced 16B stores.
// ---------------------------------------------------------------------------
__global__ __launch_bounds__(256)
void k_attn(const u16* __restrict__ qt, const u16* __restrict__ kt,
            u16* __restrict__ A16)
{
    __shared__ u16 ost[16][1032];
    __shared__ float red[4][16];
    const int b  = blockIdx.y;
    const int n0 = blockIdx.x * 16;
    const int tid = threadIdx.x, lane = tid & 63, w = tid >> 6;
    const u16* qb = qt + (size_t)b * HW_ * F_;
    const u16* kb = kt + (size_t)b * HW_ * F_;

    bf16x8 af[4];
    #pragma unroll
    for (int ks = 0; ks < 4; ks++)
        af[ks] = *(const bf16x8*)(qb + (size_t)(n0 + (lane & 15)) * F_
                                  + ks * 32 + (lane >> 4) * 8);

    f32x4 acc[16];
    #pragma unroll
    for (int j = 0; j < 16; j++) acc[j] = (f32x4){0.f, 0.f, 0.f, 0.f};

    #pragma unroll
    for (int j = 0; j < 16; j++) {
        const int m0 = w * 256 + j * 16;
        #pragma unroll
        for (int ks = 0; ks < 4; ks++) {
            bf16x8 bg = *(const bf16x8*)(kb + (size_t)(m0 + (lane & 15)) * F_
                                         + ks * 32 + (lane >> 4) * 8);
            acc[j] = __builtin_amdgcn_mfma_f32_16x16x32_bf16(
                af[ks], bg, acc[j], 0, 0, 0);
        }
    }

    float rmax[4];
    #pragma unroll
    for (int r = 0; r < 4; r++) {
        float m = acc[0][r];
        #pragma unroll
        for (int j = 1; j < 16; j++) m = fmaxf(m, acc[j][r]);
        #pragma unroll
        for (int off = 1; off < 16; off <<= 1) m = fmaxf(m, __shfl_xor(m, off));
        rmax[r] = m;
    }
    if ((lane & 15) == 0)
        #pragma unroll
        for (int r = 0; r < 4; r++) red[w][(lane >> 4) * 4 + r] = rmax[r];
    __syncthreads();
    #pragma unroll
    for (int r = 0; r < 4; r++) {
        int row = (lane >> 4) * 4 + r;
        rmax[r] = fmaxf(fmaxf(red[0][row], red[1][row]),
                        fmaxf(red[2][row], red[3][row]));
    }
    __syncthreads();

    float rsum[4];
    #pragma unroll
    for (int r = 0; r < 4; r++) {
        float s = 0.f;
        #pragma unroll
        for (int j = 0; j < 16; j++) {
            acc[j][r] = __expf(acc[j][r] - rmax[r]);
            s += acc[j][r];
        }
        #pragma unroll
        for (int off = 1; off < 16; off <<= 1) s += __shfl_xor(s, off);
        rsum[r] = s;
    }
    if ((lane & 15) == 0)
        #pragma unroll
        for (int r = 0; r < 4; r++) red[w][(lane >> 4) * 4 + r] = rsum[r];
    __syncthreads();

    #pragma unroll
    for (int r = 0; r < 4; r++) {
        int row = (lane >> 4) * 4 + r;
        float inv = 1.0f / (red[0][row] + red[1][row] +
                            red[2][row] + red[3][row]);
        #pragma unroll
        for (int j = 0; j < 16; j++)
            ost[row][w * 256 + j * 16 + (lane & 15)] = f2bf(acc[j][r] * inv);
    }
    __syncthreads();

    u16* ob = A16 + ((size_t)b * HW_ + n0) * HW_;
    #pragma unroll
    for (int it = 0; it < 8; it++) {
        int lin = it * 256 + tid;              // 0..2047
        int row = lin >> 7, g = lin & 127;
        *(u16x8*)&ob[(size_t)row * HW_ + g * 8] = *(const u16x8*)&ost[row][g * 8];
    }
}

// ---------------------------------------------------------------------------
// PV MFMA, double-buffered; output staged via LDS (reuses As) -> 16B stores.
// ---------------------------------------------------------------------------
__global__ __launch_bounds__(256)
void k_pv(const u16* __restrict__ v16, const u16* __restrict__ A16,
          const float* __restrict__ gamma_pam, u16* __restrict__ pam16)
{
    __shared__ char As[2][16384];
    __shared__ char Bs[2][16384];
    const int b   = blockIdx.z;
    const int ct0 = blockIdx.y * 128, n0 = blockIdx.x * 128;
    const int tid = threadIdx.x, lane = tid & 63, w = tid >> 6;
    const u16* vb = v16 + (size_t)b * CT_ * HW_;
    const u16* ab = A16 + (size_t)b * HW_ * HW_;

    const int s_row = (lane >> 3);
    const int s_col = ((lane & 7) ^ ((lane >> 3) & 7)) * 8;

    const int wr = w >> 1, wc = w & 1;
    f32x4 acc[4][4];
    #pragma unroll
    for (int mi = 0; mi < 4; mi++)
        #pragma unroll
        for (int ni = 0; ni < 4; ni++) acc[mi][ni] = (f32x4){0.f, 0.f, 0.f, 0.f};

    #pragma unroll
    for (int i = 0; i < 4; i++) {
        int c = w * 4 + i;
        int row = c * 8 + s_row;
        GLOAD16(vb + (size_t)(ct0 + row) * HW_ + s_col, As[0] + c * 1024);
        GLOAD16(ab + (size_t)(n0  + row) * HW_ + s_col, Bs[0] + c * 1024);
    }
    __syncthreads();

    int cur = 0;
    for (int it = 0; it < 16; ++it) {
        if (it < 15) {
            int mc = (it + 1) * 64;
            #pragma unroll
            for (int i = 0; i < 4; i++) {
                int c = w * 4 + i;
                int row = c * 8 + s_row;
                GLOAD16(vb + (size_t)(ct0 + row) * HW_ + mc + s_col,
                        As[cur ^ 1] + c * 1024);
                GLOAD16(ab + (size_t)(n0  + row) * HW_ + mc + s_col,
                        Bs[cur ^ 1] + c * 1024);
            }
        }
        const char* Ac = As[cur];
        const char* Bc = Bs[cur];
        #pragma unroll
        for (int ks = 0; ks < 2; ks++) {
            bf16x8 af[4], bg[4];
            #pragma unroll
            for (int mi = 0; mi < 4; mi++) {
                int row  = wr * 64 + mi * 16 + (lane & 15);
                int slot = (ks * 4 + (lane >> 4)) ^ (row & 7);
                af[mi] = *(const bf16x8*)(Ac + row * 128 + slot * 16);
                int rb  = wc * 64 + mi * 16 + (lane & 15);
                int sb  = (ks * 4 + (lane >> 4)) ^ (rb & 7);
                bg[mi] = *(const bf16x8*)(Bc + rb * 128 + sb * 16);
            }
            #pragma unroll
            for (int mi = 0; mi < 4; mi++)
                #pragma unroll
                for (int ni = 0; ni < 4; ni++)
                    acc[mi][ni] = __builtin_amdgcn_mfma_f32_16x16x32_bf16(
                        af[mi], bg[ni], acc[mi][ni], 0, 0, 0);
        }
        __syncthreads();
        cur ^= 1;
    }

    const float gp = gamma_pam[0];
    u16* ot = (u16*)As;                        // 128 ct x 128 n staging
    #pragma unroll
    for (int mi = 0; mi < 4; mi++)
        #pragma unroll
        for (int ni = 0; ni < 4; ni++)
            #pragma unroll
            for (int r = 0; r < 4; r++)
                ot[(wr * 64 + mi * 16 + (lane >> 4) * 4 + r) * 128 +
                   wc * 64 + ni * 16 + (lane & 15)] = f2bf(gp * acc[mi][ni][r]);
    __syncthreads();

    u16* ob = pam16 + (size_t)b * CT_ * HW_;
    #pragma unroll
    for (int it = 0; it < 8; it++) {
        int lin = it * 256 + tid;              // 0..2047
        int row = lin >> 4, col = (lin & 15) * 8;
        *(u16x8*)&ob[(size_t)(ct0 + row) * HW_ + n0 + col] =
            *(const u16x8*)&ot[row * 128 + col];
    }
}

// ---------------------------------------------------------------------------
// CAM gram via split-precision MFMA: hi.hi + hi.lo + lo.hi.
// ---------------------------------------------------------------------------
__global__ __launch_bounds__(256)
void k_cam_gram(const u16* __restrict__ xhi, const u16* __restrict__ xlo,
                float* __restrict__ part)
{
    __shared__ char Sh[32768];
    __shared__ char Sl[32768];
    const int b = blockIdx.y, ch = blockIdx.x;
    const int tid = threadIdx.x, lane = tid & 63, w = tid >> 6;
    const u16* hb = xhi + (size_t)b * C_ * P_;
    const u16* lb = xlo + (size_t)b * C_ * P_;

    f32x4 acc[8][2];
    #pragma unroll
    for (int mi = 0; mi < 8; mi++) {
        acc[mi][0] = (f32x4){0.f, 0.f, 0.f, 0.f};
        acc[mi][1] = (f32x4){0.f, 0.f, 0.f, 0.f};
    }

    for (int kc = 0; kc < 2; kc++) {
        int n0 = ch * 256 + kc * 128;
        #pragma unroll
        for (int i = 0; i < 8; i++) {
            int c4  = w * 8 + i;
            int row = c4 * 4 + (lane >> 4);
            int col = ((lane & 15) ^ (row & 7)) * 8;
            GLOAD16(hb + (size_t)row * P_ + n0 + col, Sh + c4 * 1024);
            GLOAD16(lb + (size_t)row * P_ + n0 + col, Sl + c4 * 1024);
        }
        __syncthreads();
        #pragma unroll
        for (int ks = 0; ks < 4; ks++) {
            bf16x8 bh[2], bl[2];
            #pragma unroll
            for (int ni = 0; ni < 2; ni++) {
                int rb = w * 32 + ni * 16 + (lane & 15);
                int sb = (ks * 4 + (lane >> 4)) ^ (rb & 7);
                bh[ni] = *(const bf16x8*)(Sh + rb * 256 + sb * 16);
                bl[ni] = *(const bf16x8*)(Sl + rb * 256 + sb * 16);
            }
            #pragma unroll
            for (int mi = 0; mi < 8; mi++) {
                int ra = mi * 16 + (lane & 15);
                int sa = (ks * 4 + (lane >> 4)) ^ (ra & 7);
                bf16x8 ah = *(const bf16x8*)(Sh + ra * 256 + sa * 16);
                bf16x8 al = *(const bf16x8*)(Sl + ra * 256 + sa * 16);
                #pragma unroll
                for (int ni = 0; ni < 2; ni++) {
                    acc[mi][ni] = __builtin_amdgcn_mfma_f32_16x16x32_bf16(
                        ah, bh[ni], acc[mi][ni], 0, 0, 0);
                    acc[mi][ni] = __builtin_amdgcn_mfma_f32_16x16x32_bf16(
                        ah, bl[ni], acc[mi][ni], 0, 0, 0);
                    acc[mi][ni] = __builtin_amdgcn_mfma_f32_16x16x32_bf16(
                        al, bh[ni], acc[mi][ni], 0, 0, 0);
                }
            }
        }
        __syncthreads();
    }

    float* pb = part + ((size_t)(b * 32 + ch)) * 16384;
    #pragma unroll
    for (int mi = 0; mi < 8; mi++)
        #pragma unroll
        for (int ni = 0; ni < 2; ni++)
            #pragma unroll
            for (int r = 0; r < 4; r++) {
                int c = mi * 16 + (lane >> 4) * 4 + r;
                int d = w * 32 + ni * 16 + (lane & 15);
                pb[c * 128 + d] = acc[mi][ni][r];
            }
}

// ---------------------------------------------------------------------------
// CAM reduce + negated softmax -> bf16, pre-scaled by gamma_cam.
// ---------------------------------------------------------------------------
__global__ __launch_bounds__(128)
void k_cam_reduce(const float* __restrict__ part,
                  const float* __restrict__ gamma_cam, u16* __restrict__ acam16)
{
    const int b = blockIdx.y, c = blockIdx.x;
    const int d = threadIdx.x;
    float s = 0.f;
    for (int ch = 0; ch < 32; ch++)
        s += part[(((size_t)(b * 32 + ch)) * C_ + c) * C_ + d];
    float mn = s;
    #pragma unroll
    for (int off = 32; off; off >>= 1) mn = fminf(mn, __shfl_xor(mn, off));
    __shared__ float m1[2], m2[2];
    if ((d & 63) == 0) m1[d >> 6] = mn;
    __syncthreads();
    mn = fminf(m1[0], m1[1]);
    float p = __expf(mn - s);
    float sum = p;
    #pragma unroll
    for (int off = 32; off; off >>= 1) sum += __shfl_xor(sum, off);
    if ((d & 63) == 0) m2[d >> 6] = sum;
    __syncthreads();
    sum = m2[0] + m2[1];
    acam16[((size_t)(b * C_ + c)) * C_ + d] = f2bf(gamma_cam[0] * p / sum);
}

// ---------------------------------------------------------------------------
// X' = 3x + gt*(TIM t-mix of x) -> bf16. TIM softmax computed inline from e_t.
// ---------------------------------------------------------------------------
__global__ __launch_bounds__(256)
void k_xprime(const float* __restrict__ x, const float* __restrict__ e_t,
              const float* __restrict__ gamma_tim, u16* __restrict__ Xp)
{
    const int b = blockIdx.y, c = blockIdx.x;
    const size_t base = ((size_t)(b * C_ + c)) * P_;
    const int tid = threadIdx.x;
    const float gt = gamma_tim[0];

    float4 xv[8];
    #pragma unroll
    for (int t = 0; t < 8; t++)
        xv[t] = *(const float4*)&x[base + t * HW_ + tid * 4];

    #pragma unroll
    for (int t = 0; t < 8; t++) {
        float e[8];
        #pragma unroll
        for (int s = 0; s < 8; s++) e[s] = e_t[b * 64 + t * 8 + s];
        float mn = e[0];
        #pragma unroll
        for (int s = 1; s < 8; s++) mn = fminf(mn, e[s]);
        float p[8], sum = 0.f;
        #pragma unroll
        for (int s = 0; s < 8; s++) { p[s] = __expf(mn - e[s]); sum += p[s]; }
        float inv = gt / sum;

        float4 o = make_float4(3.f * xv[t].x, 3.f * xv[t].y,
                               3.f * xv[t].z, 3.f * xv[t].w);
        #pragma unroll
        for (int s = 0; s < 8; s++) {
            float wgt = p[s] * inv;
            o.x += wgt * xv[s].x; o.y += wgt * xv[s].y;
            o.z += wgt * xv[s].z; o.w += wgt * xv[s].w;
        }
        ushort4 pk;
        pk.x = f2bf(o.x); pk.y = f2bf(o.y); pk.z = f2bf(o.z); pk.w = f2bf(o.w);
        *(ushort4*)&Xp[base + t * HW_ + tid * 4] = pk;
    }
}

// ---------------------------------------------------------------------------
// CAM AV MFMA + final combine: out = pam16 + acam16 @ x + X'.  Single store.
// ---------------------------------------------------------------------------
__global__ __launch_bounds__(256)
void k_cam_av(const u16* __restrict__ acam16, const u16* __restrict__ xT,
              const u16* __restrict__ Xp, const u16* __restrict__ pam16,
              float* __restrict__ out)
{
    const int b  = blockIdx.y;
    const int p0 = blockIdx.x * 128;
    const int tid = threadIdx.x, lane = tid & 63, w = tid >> 6;

    const u16* Ab = acam16 + (size_t)b * C_ * C_;
    const u16* Bb = xT + ((size_t)(b * P_ + p0 + w * 32)) * C_;

    f32x4 acc[8][2];
    #pragma unroll
    for (int mi = 0; mi < 8; mi++) {
        acc[mi][0] = (f32x4){0.f, 0.f, 0.f, 0.f};
        acc[mi][1] = (f32x4){0.f, 0.f, 0.f, 0.f};
    }

    bf16x8 bg[4][2];
    #pragma unroll
    for (int ks = 0; ks < 4; ks++)
        #pragma unroll
        for (int ni = 0; ni < 2; ni++)
            bg[ks][ni] = *(const bf16x8*)(Bb +
                (size_t)(ni * 16 + (lane & 15)) * C_ + ks * 32 + (lane >> 4) * 8);

    #pragma unroll
    for (int mi = 0; mi < 8; mi++) {
        #pragma unroll
        for (int ks = 0; ks < 4; ks++) {
            bf16x8 af = *(const bf16x8*)(Ab +
                (size_t)(mi * 16 + (lane & 15)) * C_ + ks * 32 + (lane >> 4) * 8);
            acc[mi][0] = __builtin_amdgcn_mfma_f32_16x16x32_bf16(
                af, bg[ks][0], acc[mi][0], 0, 0, 0);
            acc[mi][1] = __builtin_amdgcn_mfma_f32_16x16x32_bf16(
                af, bg[ks][1], acc[mi][1], 0, 0, 0);
        }
    }

    const int tt = p0 >> 10;
    float* ob = out + (size_t)b * C_ * P_;
    const u16* xp = Xp + (size_t)b * C_ * P_;
    const u16* pb = pam16 + (size_t)b * CT_ * HW_;
    #pragma unroll
    for (int mi = 0; mi < 8; mi++)
        #pragma unroll
        for (int ni = 0; ni < 2; ni++)
            #pragma unroll
            for (int r = 0; r < 4; r++) {
                int c = mi * 16 + (lane >> 4) * 4 + r;
                int p = p0 + w * 32 + ni * 16 + (lane & 15);
                int hw = p & 1023;
                size_t i = (size_t)c * P_ + p;
                float pam = bf2f(pb[((size_t)(c * 8 + tt)) * HW_ + hw]);
                ob[i] = pam + acc[mi][ni][r] + bf2f(xp[i]);
            }
}

// ---------------------------------------------------------------------------
extern "C" void kernel_launch(void* const* d_in, const int* in_sizes, int n_in,
                              void* d_out, int out_size, void* d_ws, size_t ws_size,
                              hipStream_t stream)
{
    (void)in_sizes; (void)n_in; (void)out_size; (void)ws_size;
    const float* x  = (const float*)d_in[0];
    const float* Wq = (const float*)d_in[1];
    const float* bq = (const float*)d_in[2];
    const float* Wk = (const float*)d_in[3];
    const float* bk = (const float*)d_in[4];
    const float* Wv = (const float*)d_in[5];
    const float* bv = (const float*)d_in[6];
    const float* gp = (const float*)d_in[7];
    const float* gc = (const float*)d_in[8];
    const float* gt = (const float*)d_in[9];
    float* out = (float*)d_out;
    char*  ws  = (char*)d_ws;

    const size_t MiB = 1u << 20;
    u16*   xT     = (u16*)(ws + 0);            // 16 MiB
    u16*   v16    = (u16*)(ws + 16 * MiB);     // 16 MiB
    u16*   xhi    = (u16*)(ws + 32 * MiB);     // 16 MiB
    u16*   xlo    = (u16*)(ws + 48 * MiB);     // 16 MiB
    u16*   A16    = (u16*)(ws + 64 * MiB);     // 16 MiB
    u16*   pam16  = (u16*)(ws + 80 * MiB);     // 16 MiB
    float* part   = (float*)(ws + 96 * MiB);   // 16.8 MiB
    u16*   Xp16   = (u16*)(ws + 113 * MiB);    // 16 MiB
    u16*   qtb    = (u16*)(ws + 130 * MiB);    // 2 MiB
    u16*   ktb    = (u16*)(ws + 132 * MiB);    // 2 MiB
    u16*   acam16 = (u16*)(ws + 134 * MiB);    // 32 KB
    u16*   Wall   = (u16*)(ws + 134 * MiB + 65536);   // 40 KB
    float* etim   = (float*)(ws + 134 * MiB + 131072);

    hipMemsetAsync(etim, 0, 512 * sizeof(float), stream);

    k_tim_gram  <<<dim3(64, 8),   256, 0, stream>>>(x, etim,                 // 1
                                                    Wq, Wk, Wv, Wall);
    k_prep      <<<dim3(64, 8),   256, 0, stream>>>(x, xT, xhi, xlo, Wall,   // 2
                                                    bq, bk, bv,
                                                    qtb, ktb, v16);
    k_attn      <<<dim3(64, 8),   256, 0, stream>>>(qtb, ktb, A16);          // 3
    k_pv        <<<dim3(8, 8, 8), 256, 0, stream>>>(v16, A16, gp, pam16);    // 4
    k_xprime    <<<dim3(128, 8),  256, 0, stream>>>(x, etim, gt, Xp16);      // 5
    k_cam_gram  <<<dim3(32, 8),   256, 0, stream>>>(xhi, xlo, part);         // 6
    k_cam_reduce<<<dim3(128, 8),  128, 0, stream>>>(part, gc, acam16);       // 7
    k_cam_av    <<<dim3(64, 8),   256, 0, stream>>>(acam16, xT, Xp16,        // 8
                                                    pam16, out);
}

// Round 9
// 261.527 us; speedup vs baseline: 1.0267x; 1.0267x over previous
//
#include <hip/hip_runtime.h>
#include <cstdint>

typedef unsigned short u16;
typedef __attribute__((ext_vector_type(8))) short bf16x8;
typedef __attribute__((ext_vector_type(8))) unsigned short u16x8;
typedef __attribute__((ext_vector_type(4))) float f32x4;

constexpr int B_  = 8;
constexpr int C_  = 128;
constexpr int T_  = 8;
constexpr int HW_ = 1024;
constexpr int P_  = T_ * HW_;   // 8192 positions per (b,c)
constexpr int F_  = 128;        // PAM feature dim (K-order: f'' = t*16 + cq)
constexpr int CT_ = C_ * T_;    // 1024

static __device__ __forceinline__ u16 f2bf(float f) {
    union { float f; unsigned u; } v; v.f = f;
    unsigned r = v.u + 0x7fffu + ((v.u >> 16) & 1u);   // RNE
    return (u16)(r >> 16);
}
static __device__ __forceinline__ float bf2f(u16 h) {
    union { unsigned u; float f; } v; v.u = ((unsigned)h) << 16;
    return v.f;
}

#define GLOAD16(src, dst)                                                     \
    __builtin_amdgcn_global_load_lds(                                         \
        (const __attribute__((address_space(1))) void*)(src),                 \
        (__attribute__((address_space(3))) void*)(dst), 16, 0, 0)

// ---------------------------------------------------------------------------
// TIM gram: 1 channel/block, grid (128,8) = 1024 blocks for occupancy.
// float4 loads, 36 upper-triangle accumulators. Block (0,0) casts Wall.
// ---------------------------------------------------------------------------
__global__ __launch_bounds__(256)
void k_tim_gram(const float* __restrict__ x, float* __restrict__ e_t,
                const float* __restrict__ Wq, const float* __restrict__ Wk,
                const float* __restrict__ Wv, u16* __restrict__ Wall)
{
    const int b = blockIdx.y, c = blockIdx.x;
    const int tid = threadIdx.x;

    if (c == 0 && b == 0) {
        for (int i = tid; i < 20480; i += 256) {
            int oc = i >> 7, c2 = i & 127;
            float wv;
            if (oc < 16)      wv = Wq[oc * 128 + c2];
            else if (oc < 32) wv = Wk[(oc - 16) * 128 + c2];
            else              wv = Wv[(oc - 32) * 128 + c2];
            Wall[i] = f2bf(wv);
        }
    }

    const float* xb = x + ((size_t)(b * C_ + c)) * P_;
    const int hw = tid * 4;
    float4 xv[8];
    #pragma unroll
    for (int t = 0; t < 8; t++)
        xv[t] = *(const float4*)&xb[t * HW_ + hw];

    float acc[36];
    {
        int p = 0;
        #pragma unroll
        for (int t = 0; t < 8; t++)
            #pragma unroll
            for (int s = t; s < 8; s++) {
                float4 a = xv[t], c4 = xv[s];
                acc[p++] = a.x * c4.x + a.y * c4.y + a.z * c4.z + a.w * c4.w;
            }
    }

    const int lane = tid & 63, w = tid >> 6;
    #pragma unroll
    for (int p = 0; p < 36; p++)
        #pragma unroll
        for (int off = 32; off; off >>= 1)
            acc[p] += __shfl_xor(acc[p], off);

    __shared__ float sm[4][36];
    if (lane == 0)
        #pragma unroll
        for (int p = 0; p < 36; p++) sm[w][p] = acc[p];
    __syncthreads();
    if (tid < 36) {
        float v = sm[0][tid] + sm[1][tid] + sm[2][tid] + sm[3][tid];
        int t = 0, rem = tid;
        while (rem >= 8 - t) { rem -= 8 - t; t++; }
        int s = t + rem;
        atomicAdd(&e_t[b * 64 + t * 8 + s], v);
        if (s != t) atomicAdd(&e_t[b * 64 + s * 8 + t], v);
    }
}

// ---------------------------------------------------------------------------
// FAT prep: block = (b, 16-hw slice) covering ALL 8 t x 128 c.
// One x read produces: xT[p][c], Xp = 3x+gt*TIMmix (has all t!), and
// q/k/v via MFMA from the LDS x-tile. All outputs LDS-staged, 16B stores.
// pidx = t*16 + hwj  (128 positions per block).
// ---------------------------------------------------------------------------
__global__ __launch_bounds__(256)
void k_prep(const float* __restrict__ x, const float* __restrict__ e_t,
            const u16* __restrict__ Wall,
            const float* __restrict__ bq, const float* __restrict__ bk,
            const float* __restrict__ bv, const float* __restrict__ gamma_tim,
            u16* __restrict__ xT, u16* __restrict__ qt, u16* __restrict__ kt,
            u16* __restrict__ v16, u16* __restrict__ Xp)
{
    __shared__ char sy[32768];                 // [128 pidx][128 c] bf16, swz
    __shared__ u16  qk[4096];                  // [2][16 hwj][128 f''] 8KB
    __shared__ float wgt[8][8];
    const int b   = blockIdx.y;
    const int hw0 = blockIdx.x * 16;
    const int tid = threadIdx.x, lane = tid & 63, w = tid >> 6;

    // phase 1: x -> sy (bf16, swizzled)
    #pragma unroll
    for (int r = 0; r < 16; r++) {
        int lin = r * 256 + tid;               // 0..4095
        int c = lin >> 5;
        int rem = lin & 31;
        int t = rem >> 2, j4 = (rem & 3) << 2;
        float4 xv = *(const float4*)&x[((size_t)(b * C_ + c)) * P_
                                       + t * HW_ + hw0 + j4];
        float a4[4] = {xv.x, xv.y, xv.z, xv.w};
        #pragma unroll
        for (int u = 0; u < 4; u++) {
            int pidx = t * 16 + j4 + u;
            int byte = pidx * 256 + ((c * 2) ^ (((pidx >> 2) & 15) << 4));
            *(u16*)(sy + byte) = f2bf(a4[u]);
        }
    }
    if (tid < 8) {                             // TIM softmax row tid
        float e[8];
        #pragma unroll
        for (int s = 0; s < 8; s++) e[s] = e_t[b * 64 + tid * 8 + s];
        float mn = e[0];
        #pragma unroll
        for (int s = 1; s < 8; s++) mn = fminf(mn, e[s]);
        float p[8], sum = 0.f;
        #pragma unroll
        for (int s = 0; s < 8; s++) { p[s] = __expf(mn - e[s]); sum += p[s]; }
        float inv = gamma_tim[0] / sum;
        #pragma unroll
        for (int s = 0; s < 8; s++) wgt[tid][s] = p[s] * inv;
    }
    __syncthreads();

    // phase 2: xT out (coalesced full rows)
    #pragma unroll
    for (int r = 0; r < 8; r++) {
        int lin = r * 256 + tid;
        int pi = lin >> 4, ci8 = (lin & 15) << 3;
        bf16x8 v = *(const bf16x8*)(sy + pi * 256 +
                                    ((ci8 * 2) ^ (((pi >> 2) & 15) << 4)));
        int pg = (pi >> 4) * HW_ + hw0 + (pi & 15);
        *(bf16x8*)&xT[((size_t)(b * P_ + pg)) * C_ + ci8] = v;
    }

    // phase 3: Xp = 3x + TIM t-mix (thread: c = tid>>1, 8-hwj group g)
    {
        int c = tid >> 1, g = tid & 1;
        float xsv[8][8];
        #pragma unroll
        for (int t = 0; t < 8; t++)
            #pragma unroll
            for (int k = 0; k < 8; k++) {
                int pidx = t * 16 + g * 8 + k;
                int byte = pidx * 256 + ((c * 2) ^ (((pidx >> 2) & 15) << 4));
                xsv[t][k] = bf2f(*(const u16*)(sy + byte));
            }
        #pragma unroll
        for (int t = 0; t < 8; t++) {
            u16x8 pk;
            #pragma unroll
            for (int k = 0; k < 8; k++) {
                float o = 3.f * xsv[t][k];
                #pragma unroll
                for (int s = 0; s < 8; s++) o += wgt[t][s] * xsv[s][k];
                pk[k] = f2bf(o);
            }
            *(u16x8*)&Xp[((size_t)(b * C_ + c)) * P_ + t * HW_ + hw0 + g * 8] = pk;
        }
    }

    // phase 4: B fragments from sy
    bf16x8 bg[4][2];
    #pragma unroll
    for (int ks = 0; ks < 4; ks++)
        #pragma unroll
        for (int ni = 0; ni < 2; ni++) {
            int p  = w * 32 + ni * 16 + (lane & 15);
            int cb = (ks * 32 + (lane >> 4) * 8) * 2;
            bg[ks][ni] = *(const bf16x8*)(sy + p * 256 +
                              (cb ^ (((p >> 2) & 15) << 4)));
        }
    __syncthreads();                           // sy reads done -> reusable

    // phase 5: QKV MFMA (A = Wall, L2-hot)
    f32x4 acc[10][2];
    #pragma unroll
    for (int mi = 0; mi < 10; mi++) {
        acc[mi][0] = (f32x4){0.f, 0.f, 0.f, 0.f};
        acc[mi][1] = (f32x4){0.f, 0.f, 0.f, 0.f};
    }
    #pragma unroll
    for (int mi = 0; mi < 10; mi++) {
        #pragma unroll
        for (int ks = 0; ks < 4; ks++) {
            bf16x8 af = *(const bf16x8*)(Wall + (mi * 16 + (lane & 15)) * 128
                                          + ks * 32 + (lane >> 4) * 8);
            acc[mi][0] = __builtin_amdgcn_mfma_f32_16x16x32_bf16(
                af, bg[ks][0], acc[mi][0], 0, 0, 0);
            acc[mi][1] = __builtin_amdgcn_mfma_f32_16x16x32_bf16(
                af, bg[ks][1], acc[mi][1], 0, 0, 0);
        }
    }

    // phase 6: stage q/k/v into LDS
    u16* vt = (u16*)sy;                        // [128 c][128 pidx], c-swizzled
    #pragma unroll
    for (int mi = 0; mi < 10; mi++)
        #pragma unroll
        for (int ni = 0; ni < 2; ni++)
            #pragma unroll
            for (int r = 0; r < 4; r++) {
                int oc   = mi * 16 + (lane >> 4) * 4 + r;
                int pidx = w * 32 + ni * 16 + (lane & 15);
                float bias;
                if (mi == 0)      bias = bq[oc];
                else if (mi == 1) bias = bk[oc - 16];
                else              bias = bv[oc - 32];
                u16 val = f2bf(acc[mi][ni][r] + bias);
                if (oc < 32) {
                    int m = oc >> 4, cq = oc & 15;
                    qk[m * 2048 + (pidx & 15) * 128 + (pidx >> 4) * 16 + cq] = val;
                } else {
                    int c = oc - 32;
                    int byte = c * 256 + ((pidx * 2) ^ ((c & 7) << 4));
                    *(u16*)((char*)vt + byte) = val;
                }
            }
    __syncthreads();

    // phase 7: coalesced global stores
    #pragma unroll
    for (int it = 0; it < 8; it++) {           // v: 2048 x 16B
        int lin = it * 256 + tid;
        int c = lin >> 4, tg = lin & 15;
        int t = tg >> 1, g = tg & 1;
        int pb2 = (t * 16 + g * 8) * 2;
        u16x8 vv = *(const u16x8*)(sy + c * 256 + (pb2 ^ ((c & 7) << 4)));
        *(u16x8*)&v16[((size_t)(b * C_ + c)) * P_ + t * HW_ + hw0 + g * 8] = vv;
    }
    #pragma unroll
    for (int it = 0; it < 2; it++) {           // q/k: 512 x 16B
        int lin = it * 256 + tid;
        int m = lin >> 8, hwl = (lin >> 4) & 15, ck = lin & 15;
        u16x8 vv = *(const u16x8*)&qk[m * 2048 + hwl * 128 + ck * 8];
        u16* dst = m ? kt : qt;
        *(u16x8*)&dst[((size_t)b * HW_ + hw0 + hwl) * F_ + ck * 8] = vv;
    }
}

// ---------------------------------------------------------------------------
// Fused energy+softmax: block = 16 n-rows x 1024 m, E stays in registers.
// ---------------------------------------------------------------------------
__global__ __launch_bounds__(256)
void k_attn(const u16* __restrict__ qt, const u16* __restrict__ kt,
            u16* __restrict__ A16)
{
    __shared__ u16 ost[16][1032];
    __shared__ float red[4][16];
    const int b  = blockIdx.y;
    const int n0 = blockIdx.x * 16;
    const int tid = threadIdx.x, lane = tid & 63, w = tid >> 6;
    const u16* qb = qt + (size_t)b * HW_ * F_;
    const u16* kb = kt + (size_t)b * HW_ * F_;

    bf16x8 af[4];
    #pragma unroll
    for (int ks = 0; ks < 4; ks++)
        af[ks] = *(const bf16x8*)(qb + (size_t)(n0 + (lane & 15)) * F_
                                  + ks * 32 + (lane >> 4) * 8);

    f32x4 acc[16];
    #pragma unroll
    for (int j = 0; j < 16; j++) acc[j] = (f32x4){0.f, 0.f, 0.f, 0.f};

    #pragma unroll
    for (int j = 0; j < 16; j++) {
        const int m0 = w * 256 + j * 16;
        #pragma unroll
        for (int ks = 0; ks < 4; ks++) {
            bf16x8 bg = *(const bf16x8*)(kb + (size_t)(m0 + (lane & 15)) * F_
                                         + ks * 32 + (lane >> 4) * 8);
            acc[j] = __builtin_amdgcn_mfma_f32_16x16x32_bf16(
                af[ks], bg, acc[j], 0, 0, 0);
        }
    }

    float rmax[4];
    #pragma unroll
    for (int r = 0; r < 4; r++) {
        float m = acc[0][r];
        #pragma unroll
        for (int j = 1; j < 16; j++) m = fmaxf(m, acc[j][r]);
        #pragma unroll
        for (int off = 1; off < 16; off <<= 1) m = fmaxf(m, __shfl_xor(m, off));
        rmax[r] = m;
    }
    if ((lane & 15) == 0)
        #pragma unroll
        for (int r = 0; r < 4; r++) red[w][(lane >> 4) * 4 + r] = rmax[r];
    __syncthreads();
    #pragma unroll
    for (int r = 0; r < 4; r++) {
        int row = (lane >> 4) * 4 + r;
        rmax[r] = fmaxf(fmaxf(red[0][row], red[1][row]),
                        fmaxf(red[2][row], red[3][row]));
    }
    __syncthreads();

    float rsum[4];
    #pragma unroll
    for (int r = 0; r < 4; r++) {
        float s = 0.f;
        #pragma unroll
        for (int j = 0; j < 16; j++) {
            acc[j][r] = __expf(acc[j][r] - rmax[r]);
            s += acc[j][r];
        }
        #pragma unroll
        for (int off = 1; off < 16; off <<= 1) s += __shfl_xor(s, off);
        rsum[r] = s;
    }
    if ((lane & 15) == 0)
        #pragma unroll
        for (int r = 0; r < 4; r++) red[w][(lane >> 4) * 4 + r] = rsum[r];
    __syncthreads();

    #pragma unroll
    for (int r = 0; r < 4; r++) {
        int row = (lane >> 4) * 4 + r;
        float inv = 1.0f / (red[0][row] + red[1][row] +
                            red[2][row] + red[3][row]);
        #pragma unroll
        for (int j = 0; j < 16; j++)
            ost[row][w * 256 + j * 16 + (lane & 15)] = f2bf(acc[j][r] * inv);
    }
    __syncthreads();

    u16* ob = A16 + ((size_t)b * HW_ + n0) * HW_;
    #pragma unroll
    for (int it = 0; it < 8; it++) {
        int lin = it * 256 + tid;
        int row = lin >> 7, g = lin & 127;
        *(u16x8*)&ob[(size_t)row * HW_ + g * 8] = *(const u16x8*)&ost[row][g * 8];
    }
}

// ---------------------------------------------------------------------------
// PV MFMA, double-buffered; output staged via LDS -> 16B stores.
// ---------------------------------------------------------------------------
__global__ __launch_bounds__(256)
void k_pv(const u16* __restrict__ v16, const u16* __restrict__ A16,
          const float* __restrict__ gamma_pam, u16* __restrict__ pam16)
{
    __shared__ char As[2][16384];
    __shared__ char Bs[2][16384];
    const int b   = blockIdx.z;
    const int ct0 = blockIdx.y * 128, n0 = blockIdx.x * 128;
    const int tid = threadIdx.x, lane = tid & 63, w = tid >> 6;
    const u16* vb = v16 + (size_t)b * CT_ * HW_;
    const u16* ab = A16 + (size_t)b * HW_ * HW_;

    const int s_row = (lane >> 3);
    const int s_col = ((lane & 7) ^ ((lane >> 3) & 7)) * 8;

    const int wr = w >> 1, wc = w & 1;
    f32x4 acc[4][4];
    #pragma unroll
    for (int mi = 0; mi < 4; mi++)
        #pragma unroll
        for (int ni = 0; ni < 4; ni++) acc[mi][ni] = (f32x4){0.f, 0.f, 0.f, 0.f};

    #pragma unroll
    for (int i = 0; i < 4; i++) {
        int c = w * 4 + i;
        int row = c * 8 + s_row;
        GLOAD16(vb + (size_t)(ct0 + row) * HW_ + s_col, As[0] + c * 1024);
        GLOAD16(ab + (size_t)(n0  + row) * HW_ + s_col, Bs[0] + c * 1024);
    }
    __syncthreads();

    int cur = 0;
    for (int it = 0; it < 16; ++it) {
        if (it < 15) {
            int mc = (it + 1) * 64;
            #pragma unroll
            for (int i = 0; i < 4; i++) {
                int c = w * 4 + i;
                int row = c * 8 + s_row;
                GLOAD16(vb + (size_t)(ct0 + row) * HW_ + mc + s_col,
                        As[cur ^ 1] + c * 1024);
                GLOAD16(ab + (size_t)(n0  + row) * HW_ + mc + s_col,
                        Bs[cur ^ 1] + c * 1024);
            }
        }
        const char* Ac = As[cur];
        const char* Bc = Bs[cur];
        #pragma unroll
        for (int ks = 0; ks < 2; ks++) {
            bf16x8 af[4], bg[4];
            #pragma unroll
            for (int mi = 0; mi < 4; mi++) {
                int row  = wr * 64 + mi * 16 + (lane & 15);
                int slot = (ks * 4 + (lane >> 4)) ^ (row & 7);
                af[mi] = *(const bf16x8*)(Ac + row * 128 + slot * 16);
                int rb  = wc * 64 + mi * 16 + (lane & 15);
                int sb  = (ks * 4 + (lane >> 4)) ^ (rb & 7);
                bg[mi] = *(const bf16x8*)(Bc + rb * 128 + sb * 16);
            }
            #pragma unroll
            for (int mi = 0; mi < 4; mi++)
                #pragma unroll
                for (int ni = 0; ni < 4; ni++)
                    acc[mi][ni] = __builtin_amdgcn_mfma_f32_16x16x32_bf16(
                        af[mi], bg[ni], acc[mi][ni], 0, 0, 0);
        }
        __syncthreads();
        cur ^= 1;
    }

    const float gp = gamma_pam[0];
    u16* ot = (u16*)As;
    #pragma unroll
    for (int mi = 0; mi < 4; mi++)
        #pragma unroll
        for (int ni = 0; ni < 4; ni++)
            #pragma unroll
            for (int r = 0; r < 4; r++)
                ot[(wr * 64 + mi * 16 + (lane >> 4) * 4 + r) * 128 +
                   wc * 64 + ni * 16 + (lane & 15)] = f2bf(gp * acc[mi][ni][r]);
    __syncthreads();

    u16* ob = pam16 + (size_t)b * CT_ * HW_;
    #pragma unroll
    for (int it = 0; it < 8; it++) {
        int lin = it * 256 + tid;
        int row = lin >> 4, col = (lin & 15) * 8;
        *(u16x8*)&ob[(size_t)(ct0 + row) * HW_ + n0 + col] =
            *(const u16x8*)&ot[row * 128 + col];
    }
}

// ---------------------------------------------------------------------------
// CAM gram: reads fp32 x directly, inline hi/lo split to LDS (write-side
// swizzle matches the MFMA read path). hi.hi + hi.lo + lo.hi.
// ---------------------------------------------------------------------------
__global__ __launch_bounds__(256)
void k_cam_gram(const float* __restrict__ x, float* __restrict__ part)
{
    __shared__ char Sh[32768];
    __shared__ char Sl[32768];
    const int b = blockIdx.y, ch = blockIdx.x;
    const int tid = threadIdx.x, lane = tid & 63, w = tid >> 6;
    const float* xb = x + (size_t)b * C_ * P_;

    f32x4 acc[8][2];
    #pragma unroll
    for (int mi = 0; mi < 8; mi++) {
        acc[mi][0] = (f32x4){0.f, 0.f, 0.f, 0.f};
        acc[mi][1] = (f32x4){0.f, 0.f, 0.f, 0.f};
    }

    for (int kc = 0; kc < 2; kc++) {
        int n0 = ch * 256 + kc * 128;
        #pragma unroll
        for (int r = 0; r < 16; r++) {
            int lin = r * 256 + tid;           // 0..4095
            int c = lin >> 5, j4 = (lin & 31) << 2;
            float4 xv = *(const float4*)&xb[(size_t)c * P_ + n0 + j4];
            float a4[4] = {xv.x, xv.y, xv.z, xv.w};
            ushort4 h, l;
            h.x = f2bf(a4[0]); h.y = f2bf(a4[1]);
            h.z = f2bf(a4[2]); h.w = f2bf(a4[3]);
            l.x = f2bf(a4[0] - bf2f(h.x)); l.y = f2bf(a4[1] - bf2f(h.y));
            l.z = f2bf(a4[2] - bf2f(h.z)); l.w = f2bf(a4[3] - bf2f(h.w));
            int grp = j4 >> 3, off = (j4 & 7) * 2;
            int byteb = c * 256 + ((grp ^ (c & 7)) << 4) + off;
            *(ushort4*)(Sh + byteb) = h;
            *(ushort4*)(Sl + byteb) = l;
        }
        __syncthreads();
        #pragma unroll
        for (int ks = 0; ks < 4; ks++) {
            bf16x8 bh[2], bl[2];
            #pragma unroll
            for (int ni = 0; ni < 2; ni++) {
                int rb = w * 32 + ni * 16 + (lane & 15);
                int sb = (ks * 4 + (lane >> 4)) ^ (rb & 7);
                bh[ni] = *(const bf16x8*)(Sh + rb * 256 + sb * 16);
                bl[ni] = *(const bf16x8*)(Sl + rb * 256 + sb * 16);
            }
            #pragma unroll
            for (int mi = 0; mi < 8; mi++) {
                int ra = mi * 16 + (lane & 15);
                int sa = (ks * 4 + (lane >> 4)) ^ (ra & 7);
                bf16x8 ah = *(const bf16x8*)(Sh + ra * 256 + sa * 16);
                bf16x8 al = *(const bf16x8*)(Sl + ra * 256 + sa * 16);
                #pragma unroll
                for (int ni = 0; ni < 2; ni++) {
                    acc[mi][ni] = __builtin_amdgcn_mfma_f32_16x16x32_bf16(
                        ah, bh[ni], acc[mi][ni], 0, 0, 0);
                    acc[mi][ni] = __builtin_amdgcn_mfma_f32_16x16x32_bf16(
                        ah, bl[ni], acc[mi][ni], 0, 0, 0);
                    acc[mi][ni] = __builtin_amdgcn_mfma_f32_16x16x32_bf16(
                        al, bh[ni], acc[mi][ni], 0, 0, 0);
                }
            }
        }
        __syncthreads();
    }

    float* pb = part + ((size_t)(b * 32 + ch)) * 16384;
    #pragma unroll
    for (int mi = 0; mi < 8; mi++)
        #pragma unroll
        for (int ni = 0; ni < 2; ni++)
            #pragma unroll
            for (int r = 0; r < 4; r++) {
                int c = mi * 16 + (lane >> 4) * 4 + r;
                int d = w * 32 + ni * 16 + (lane & 15);
                pb[c * 128 + d] = acc[mi][ni][r];
            }
}

// ---------------------------------------------------------------------------
// CAM reduce + negated softmax -> bf16, pre-scaled by gamma_cam.
// ---------------------------------------------------------------------------
__global__ __launch_bounds__(128)
void k_cam_reduce(const float* __restrict__ part,
                  const float* __restrict__ gamma_cam, u16* __restrict__ acam16)
{
    const int b = blockIdx.y, c = blockIdx.x;
    const int d = threadIdx.x;
    float s = 0.f;
    for (int ch = 0; ch < 32; ch++)
        s += part[(((size_t)(b * 32 + ch)) * C_ + c) * C_ + d];
    float mn = s;
    #pragma unroll
    for (int off = 32; off; off >>= 1) mn = fminf(mn, __shfl_xor(mn, off));
    __shared__ float m1[2], m2[2];
    if ((d & 63) == 0) m1[d >> 6] = mn;
    __syncthreads();
    mn = fminf(m1[0], m1[1]);
    float p = __expf(mn - s);
    float sum = p;
    #pragma unroll
    for (int off = 32; off; off >>= 1) sum += __shfl_xor(sum, off);
    if ((d & 63) == 0) m2[d >> 6] = sum;
    __syncthreads();
    sum = m2[0] + m2[1];
    acam16[((size_t)(b * C_ + c)) * C_ + d] = f2bf(gamma_cam[0] * p / sum);
}

// ---------------------------------------------------------------------------
// CAM AV MFMA + final combine: out = pam16 + acam16 @ x + Xp.  Single store.
// ---------------------------------------------------------------------------
__global__ __launch_bounds__(256)
void k_cam_av(const u16* __restrict__ acam16, const u16* __restrict__ xT,
              const u16* __restrict__ Xp, const u16* __restrict__ pam16,
              float* __restrict__ out)
{
    const int b  = blockIdx.y;
    const int p0 = blockIdx.x * 128;
    const int tid = threadIdx.x, lane = tid & 63, w = tid >> 6;

    const u16* Ab = acam16 + (size_t)b * C_ * C_;
    const u16* Bb = xT + ((size_t)(b * P_ + p0 + w * 32)) * C_;

    f32x4 acc[8][2];
    #pragma unroll
    for (int mi = 0; mi < 8; mi++) {
        acc[mi][0] = (f32x4){0.f, 0.f, 0.f, 0.f};
        acc[mi][1] = (f32x4){0.f, 0.f, 0.f, 0.f};
    }

    bf16x8 bg[4][2];
    #pragma unroll
    for (int ks = 0; ks < 4; ks++)
        #pragma unroll
        for (int ni = 0; ni < 2; ni++)
            bg[ks][ni] = *(const bf16x8*)(Bb +
                (size_t)(ni * 16 + (lane & 15)) * C_ + ks * 32 + (lane >> 4) * 8);

    #pragma unroll
    for (int mi = 0; mi < 8; mi++) {
        #pragma unroll
        for (int ks = 0; ks < 4; ks++) {
            bf16x8 af = *(const bf16x8*)(Ab +
                (size_t)(mi * 16 + (lane & 15)) * C_ + ks * 32 + (lane >> 4) * 8);
            acc[mi][0] = __builtin_amdgcn_mfma_f32_16x16x32_bf16(
                af, bg[ks][0], acc[mi][0], 0, 0, 0);
            acc[mi][1] = __builtin_amdgcn_mfma_f32_16x16x32_bf16(
                af, bg[ks][1], acc[mi][1], 0, 0, 0);
        }
    }

    const int tt = p0 >> 10;
    float* ob = out + (size_t)b * C_ * P_;
    const u16* xp = Xp + (size_t)b * C_ * P_;
    const u16* pb = pam16 + (size_t)b * CT_ * HW_;
    #pragma unroll
    for (int mi = 0; mi < 8; mi++)
        #pragma unroll
        for (int ni = 0; ni < 2; ni++)
            #pragma unroll
            for (int r = 0; r < 4; r++) {
                int c = mi * 16 + (lane >> 4) * 4 + r;
                int p = p0 + w * 32 + ni * 16 + (lane & 15);
                int hw = p & 1023;
                size_t i = (size_t)c * P_ + p;
                float pam = bf2f(pb[((size_t)(c * 8 + tt)) * HW_ + hw]);
                ob[i] = pam + acc[mi][ni][r] + bf2f(xp[i]);
            }
}

// ---------------------------------------------------------------------------
extern "C" void kernel_launch(void* const* d_in, const int* in_sizes, int n_in,
                              void* d_out, int out_size, void* d_ws, size_t ws_size,
                              hipStream_t stream)
{
    (void)in_sizes; (void)n_in; (void)out_size; (void)ws_size;
    const float* x  = (const float*)d_in[0];
    const float* Wq = (const float*)d_in[1];
    const float* bq = (const float*)d_in[2];
    const float* Wk = (const float*)d_in[3];
    const float* bk = (const float*)d_in[4];
    const float* Wv = (const float*)d_in[5];
    const float* bv = (const float*)d_in[6];
    const float* gp = (const float*)d_in[7];
    const float* gc = (const float*)d_in[8];
    const float* gt = (const float*)d_in[9];
    float* out = (float*)d_out;
    char*  ws  = (char*)d_ws;

    const size_t MiB = 1u << 20;
    u16*   xT     = (u16*)(ws + 0);            // 16 MiB
    u16*   v16    = (u16*)(ws + 16 * MiB);     // 16 MiB
    u16*   A16    = (u16*)(ws + 32 * MiB);     // 16 MiB
    u16*   pam16  = (u16*)(ws + 48 * MiB);     // 16 MiB
    float* part   = (float*)(ws + 64 * MiB);   // 16 MiB
    u16*   Xp16   = (u16*)(ws + 80 * MiB);     // 16 MiB
    u16*   qtb    = (u16*)(ws + 96 * MiB);     // 2 MiB
    u16*   ktb    = (u16*)(ws + 98 * MiB);     // 2 MiB
    u16*   acam16 = (u16*)(ws + 100 * MiB);    // 32 KB
    u16*   Wall   = (u16*)(ws + 100 * MiB + 65536);   // 40 KB
    float* etim   = (float*)(ws + 100 * MiB + 131072);

    hipMemsetAsync(etim, 0, 512 * sizeof(float), stream);

    k_tim_gram  <<<dim3(128, 8),  256, 0, stream>>>(x, etim,                 // 1
                                                    Wq, Wk, Wv, Wall);
    k_prep      <<<dim3(64, 8),   256, 0, stream>>>(x, etim, Wall,           // 2
                                                    bq, bk, bv, gt,
                                                    xT, qtb, ktb, v16, Xp16);
    k_attn      <<<dim3(64, 8),   256, 0, stream>>>(qtb, ktb, A16);          // 3
    k_pv        <<<dim3(8, 8, 8), 256, 0, stream>>>(v16, A16, gp, pam16);    // 4
    k_cam_gram  <<<dim3(32, 8),   256, 0, stream>>>(x, part);                // 5
    k_cam_reduce<<<dim3(128, 8),  128, 0, stream>>>(part, gc, acam16);       // 6
    k_cam_av    <<<dim3(64, 8),   256, 0, stream>>>(acam16, xT, Xp16,        // 7
                                                    pam16, out);
}